// Round 15
// baseline (312.731 us; speedup 1.0000x reference)
//
#include <hip/hip_runtime.h>
#include <hip/hip_bf16.h>

typedef unsigned short u16;
typedef unsigned int u32;

constexpr int kHW  = 16384;   // 128*128
constexpr int kC   = 192;
constexpr int kC3  = 576;
constexpr int kHD  = 48;
constexpr int kB   = 8;
constexpr int kSCH = 16;      // S-partial chunks (1024 n each)

typedef __attribute__((ext_vector_type(8))) short bfx8;  // 8 bf16 in 4 VGPRs
typedef __attribute__((ext_vector_type(4))) float fx4;

__device__ __forceinline__ float bfu2f(u32 u) { return __uint_as_float(u << 16); }
__device__ __forceinline__ u16 f2bfu(float f) {
  u32 x = __float_as_uint(f);
  return (u16)((x + 0x7fffu + ((x >> 16) & 1u)) >> 16);  // RNE
}
__device__ __forceinline__ u32 pack2(float a, float b) {
  union { __hip_bfloat162 h; u32 u; } cv;
  cv.h = __float22bfloat162_rn(make_float2(a, b));  // v_cvt_pk_bf16_f32
  return cv.u;
}

// ---------------------------------------------------------------------------
// P1: f32 -> bf16 cast (for w_qkv)
// ---------------------------------------------------------------------------
__global__ __launch_bounds__(256) void cast_f32_bf16(
    const float* __restrict__ in, u16* __restrict__ out, int n) {
  int i = blockIdx.x * 256 + threadIdx.x;
  if (i < n) out[i] = f2bfu(in[i]);
}

// ---------------------------------------------------------------------------
// K1/K5: MFMA GEMM, B consumed DIRECTLY from [k][n] row-major global layout.
// Out[b][o][n] = sum_k A[b?][o][k] * B[b][k][n], K = 192.
// Block tile 192o x 128n, 512 threads = 8 waves (wave-tile 48o x 64n, 4x2).
//
// ROUND-15 KEY FIX: this hipcc treats __launch_bounds__'s 2nd arg as min
// BLOCKS per CU (CUDA semantics). Evidence: (512,4) pinned VGPR_Count=64
// (= 512 regs / 8 waves-per-SIMD) in rounds 9-14; (512,6) gave 40.
// Every prefetch "spill" (r10/r12/r14) was this 64-reg cap, not the code.
// (512,2) -> 4 waves/EU -> 128-VGPR budget; the hand-peeled issue-early/
// write-late pipeline (round 14, unchanged) now fits: acc 48 + held A 12 +
// held B 16 + transient frags ~28 + addr ~10 = ~114.
//
// B LDS layout (proven round 11): [n][k-pair],
//   word(n,p) = n*32 + (((p>>2) ^ s(n))*4 + (p&3)), s(n) = (n + (n>>3))&7
//   fragment = ONE ds_read_b128, identical k-map on A and B.
// Direct epilogue (round-13 LDS-staged form falsified).
// Grid 1-D, o innermost + bijective XCD swizzle (gridDim %8==0).
// ---------------------------------------------------------------------------
template <bool IN_F32, bool OUT_BF16>
__global__ __launch_bounds__(512, 2) void gemm_cn7(
    const u16* __restrict__ Abase, long aStride,
    const void* __restrict__ Bbase, long bStride,
    void* __restrict__ OutBase, long oStride, int nOB) {
  const int nwg = (int)gridDim.x;
  const int wg = ((int)blockIdx.x & 7) * (nwg >> 3) + ((int)blockIdx.x >> 3);
  const int o0 = (wg % nOB) * 192;
  const int rest = wg / nOB;
  const int n0 = (rest & 127) * 128;
  const int b  = rest >> 7;

  const int t = threadIdx.x;
  const int lane = t & 63, wv = t >> 6;     // 8 waves
  const int wo = wv & 3, wn = wv >> 2;      // wave-grid 4(o) x 2(n)
  const int fr = lane & 15, fg = lane >> 4;

  __shared__ u16 As[192 * 64];                // [o][k] swizzled, 24 KB
  __shared__ __align__(16) u32 Bs[128 * 32];  // [n][k-pair] swizzled, 16 KB

  const u16* A = Abase + (size_t)b * aStride;
  const float* BgF = (const float*)Bbase + (size_t)b * bStride;
  const u16*  BgH = (const u16*)Bbase + (size_t)b * bStride;

  fx4 acc[3][4];
#pragma unroll
  for (int m = 0; m < 3; ++m)
#pragma unroll
    for (int n = 0; n < 4; ++n) acc[m][n] = (fx4){0.f, 0.f, 0.f, 0.f};

  const int sp = t >> 4;            // staging pair index 0..31
  const int sn8 = (t & 15) * 8;     // staging n-oct base
  const int arow = t >> 3, asl = t & 7;
  const int phi = sp >> 2, plo = sp & 3;

  // ---- inline helpers (no state; distinct regs per call site) ----
  auto loadA = [&](int k0, uint4 a[3]) {
#pragma unroll
    for (int i = 0; i < 3; ++i)
      a[i] = *(const uint4*)(A + (size_t)(o0 + arow + i * 64) * kC + k0 + asl * 8);
  };
  auto writeA = [&](const uint4 a[3]) {
#pragma unroll
    for (int i = 0; i < 3; ++i) {
      int row = arow + i * 64;
      *(uint4*)(As + row * 64 + ((asl ^ (row & 7)) * 8)) = a[i];
    }
  };
  auto loadBf = [&](int k0, float4 f[4]) {
    const float* s0 = BgF + (size_t)(k0 + 2 * sp) * kHW + n0 + sn8;
    f[0] = *(const float4*)s0;
    f[1] = *(const float4*)(s0 + 4);
    f[2] = *(const float4*)(s0 + (size_t)kHW);
    f[3] = *(const float4*)(s0 + (size_t)kHW + 4);
  };
  auto loadBh = [&](int k0, uint4 h[2]) {
    const u16* s0 = BgH + (size_t)(k0 + 2 * sp) * kHW + n0 + sn8;
    h[0] = *(const uint4*)s0;
    h[1] = *(const uint4*)(s0 + (size_t)kHW);
  };
  auto writeBf = [&](const float4 f[4]) {
    u32 w[8];
    w[0] = pack2(f[0].x, f[2].x); w[1] = pack2(f[0].y, f[2].y);
    w[2] = pack2(f[0].z, f[2].z); w[3] = pack2(f[0].w, f[2].w);
    w[4] = pack2(f[1].x, f[3].x); w[5] = pack2(f[1].y, f[3].y);
    w[6] = pack2(f[1].z, f[3].z); w[7] = pack2(f[1].w, f[3].w);
#pragma unroll
    for (int j = 0; j < 8; ++j) {
      int n = sn8 + j;
      int s = (n + (n >> 3)) & 7;
      Bs[n * 32 + (((phi ^ s) << 2) | plo)] = w[j];
    }
  };
  auto writeBh = [&](const uint4 h[2]) {
    union { uint4 u; u16 e[8]; } a, c;
    a.u = h[0]; c.u = h[1];
    u32 w[8];
#pragma unroll
    for (int j = 0; j < 8; ++j) w[j] = (u32)a.e[j] | ((u32)c.e[j] << 16);
#pragma unroll
    for (int j = 0; j < 8; ++j) {
      int n = sn8 + j;
      int s = (n + (n >> 3)) & 7;
      Bs[n * 32 + (((phi ^ s) << 2) | plo)] = w[j];
    }
  };
  auto compute = [&]() {
#pragma unroll
    for (int ks = 0; ks < 2; ++ks) {
      bfx8 af[3], bfr[4];
#pragma unroll
      for (int m = 0; m < 3; ++m) {
        int row = wo * 48 + m * 16 + fr;
        af[m] = *(const bfx8*)(As + row * 64 + (((ks * 4 + fg) ^ (row & 7)) * 8));
      }
#pragma unroll
      for (int nf = 0; nf < 4; ++nf) {
        int n = wn * 64 + nf * 16 + fr;
        int s = (n + (n >> 3)) & 7;
        union { uint4 u; bfx8 f; } cv;
        cv.u = *(const uint4*)(&Bs[n * 32 + (((ks * 4 + fg) ^ s) << 2)]);
        bfr[nf] = cv.f;
      }
#pragma unroll
      for (int m = 0; m < 3; ++m)
#pragma unroll
        for (int n = 0; n < 4; ++n)
          acc[m][n] = __builtin_amdgcn_mfma_f32_16x16x32_bf16(af[m], bfr[n], acc[m][n], 0, 0, 0);
    }
  };

  // ---- hand-peeled 3-step pipeline ----
  uint4 a0[3], a1[3], a2[3];
  float4 f0[4], f1[4], f2[4];
  uint4 h0[2], h1[2], h2[2];

  loadA(0, a0);
  if constexpr (IN_F32) loadBf(0, f0); else loadBh(0, h0);
  writeA(a0);
  if constexpr (IN_F32) writeBf(f0); else writeBh(h0);
  loadA(64, a1);                                  // step-1 loads in flight
  if constexpr (IN_F32) loadBf(64, f1); else loadBh(64, h1);
  __syncthreads();
  compute();                                      // step 0 (hides step-1 latency)
  __syncthreads();
  writeA(a1);
  if constexpr (IN_F32) writeBf(f1); else writeBh(h1);
  loadA(128, a2);                                 // step-2 loads in flight
  if constexpr (IN_F32) loadBf(128, f2); else loadBh(128, h2);
  __syncthreads();
  compute();                                      // step 1 (hides step-2 latency)
  __syncthreads();
  writeA(a2);
  if constexpr (IN_F32) writeBf(f2); else writeBh(h2);
  __syncthreads();
  compute();                                      // step 2

  // ---- direct epilogue (round-11 form) ----
  if constexpr (OUT_BF16) {
    u16* O = (u16*)OutBase + (size_t)b * oStride;
#pragma unroll
    for (int m = 0; m < 3; ++m)
#pragma unroll
      for (int n = 0; n < 4; ++n) {
        int col = n0 + wn * 64 + n * 16 + fr;
#pragma unroll
        for (int r = 0; r < 4; ++r)
          O[(size_t)(o0 + wo * 48 + m * 16 + fg * 4 + r) * kHW + col] = f2bfu(acc[m][n][r]);
      }
  } else {
    float* O = (float*)OutBase + (size_t)b * oStride;
#pragma unroll
    for (int m = 0; m < 3; ++m)
#pragma unroll
      for (int n = 0; n < 4; ++n) {
        int col = n0 + wn * 64 + n * 16 + fr;
#pragma unroll
        for (int r = 0; r < 4; ++r)
          O[(size_t)(o0 + wo * 48 + m * 16 + fg * 4 + r) * kHW + col] = acc[m][n][r];
      }
  }
}

// ---------------------------------------------------------------------------
// K2: depthwise 3x3 'SAME'. 8 output rows x 8 cols per thread, rolling row
// window; halo cols come from neighbor lanes via shfl (no scalar loads).
// Emits per-plane sum-of-squares for q,k channels.
// ---------------------------------------------------------------------------
__device__ __forceinline__ void load_row3(const u16* __restrict__ plane, int hh,
                                          int w8, float v[10]) {
  uint4 m = make_uint4(0u, 0u, 0u, 0u);
  if ((unsigned)hh <= 127u) m = *(const uint4*)(plane + hh * 128 + w8 * 8);
  u32 left  = __shfl_up(m.w >> 16, 1);        // prev lane's last col
  u32 right = __shfl_down(m.x & 0xffffu, 1);  // next lane's first col
  v[1] = bfu2f(m.x & 0xffffu); v[2] = bfu2f(m.x >> 16);
  v[3] = bfu2f(m.y & 0xffffu); v[4] = bfu2f(m.y >> 16);
  v[5] = bfu2f(m.z & 0xffffu); v[6] = bfu2f(m.z >> 16);
  v[7] = bfu2f(m.w & 0xffffu); v[8] = bfu2f(m.w >> 16);
  v[0] = (w8 > 0)  ? bfu2f(left)  : 0.f;
  v[9] = (w8 < 15) ? bfu2f(right) : 0.f;
}

__global__ __launch_bounds__(256) void dwconv3x3_v3(
    const u16* __restrict__ in, const float* __restrict__ wdw,
    u16* __restrict__ out, float* __restrict__ ssqp) {
  const int bc = blockIdx.x;            // plane index b*576+ch
  const int ch = bc % kC3;
  const int t = threadIdx.x;
  const int w8 = t & 15;
  const int h0 = (t >> 4) * 8;
  const u16* p = in + (size_t)bc * kHW;
  float wt[9];
#pragma unroll
  for (int j = 0; j < 9; ++j) wt[j] = wdw[ch * 9 + j];

  float v[3][10];
  load_row3(p, h0 - 1, w8, v[0]);
  load_row3(p, h0,     w8, v[1]);
  float ssq = 0.f;
  u16* op = out + (size_t)bc * kHW + h0 * 128 + w8 * 8;
#pragma unroll
  for (int r = 0; r < 8; ++r) {
    load_row3(p, h0 + r + 1, w8, v[(r + 2) % 3]);
    const float* r0 = v[r % 3];
    const float* r1 = v[(r + 1) % 3];
    const float* r2 = v[(r + 2) % 3];
    float o[8];
#pragma unroll
    for (int j = 0; j < 8; ++j) {
      o[j] = wt[0] * r0[j] + wt[1] * r0[j + 1] + wt[2] * r0[j + 2]
           + wt[3] * r1[j] + wt[4] * r1[j + 1] + wt[5] * r1[j + 2]
           + wt[6] * r2[j] + wt[7] * r2[j + 1] + wt[8] * r2[j + 2];
      ssq += o[j] * o[j];
    }
    *(uint4*)(op + r * 128) = make_uint4(pack2(o[0], o[1]), pack2(o[2], o[3]),
                                         pack2(o[4], o[5]), pack2(o[6], o[7]));
  }
  if (ch < 2 * kC) {  // q,k channels: block-uniform branch
#pragma unroll
    for (int d = 1; d < 64; d <<= 1) ssq += __shfl_xor(ssq, d);
    __shared__ float red[4];
    if ((t & 63) == 0) red[t >> 6] = ssq;
    __syncthreads();
    if (t == 0) ssqp[bc] = red[0] + red[1] + red[2] + red[3];
  }
}

// ---------------------------------------------------------------------------
// K3: LDS-staged MFMA split-K of S = q k^T. Block = (chunk of 1024 n, bh).
// ---------------------------------------------------------------------------
__global__ __launch_bounds__(256) void qk_mfma_lds(
    const u16* __restrict__ qkv2, float* __restrict__ Spart) {
  const int chunk = blockIdx.x;   // 0..15
  const int bh = blockIdx.y;      // 0..31
  const int b = bh >> 2, hh = bh & 3;
  const u16* qp = qkv2 + (size_t)(b * kC3 + hh * kHD) * kHW;
  const u16* kp = qp + (size_t)kC * kHW;

  __shared__ u16 smem[24576];     // 48 KB: qs | ks; sred aliases
  u16* qs = smem;
  u16* ks = smem + 12288;
  float* sred = (float*)smem;

  const int t = threadIdx.x;
  const int wv = t >> 6, lane = t & 63;
  const int fr = lane & 15, fg = lane >> 4;

  fx4 acc[3][3];
#pragma unroll
  for (int i = 0; i < 3; ++i)
#pragma unroll
    for (int j = 0; j < 3; ++j) acc[i][j] = (fx4){0.f, 0.f, 0.f, 0.f};

  for (int round = 0; round < 4; ++round) {
    if (round) __syncthreads();
    const int nb = chunk * 1024 + round * 256;
#pragma unroll
    for (int j = 0; j < 6; ++j) {   // 1536 uint4 per operand
      int idx = t + j * 256;
      int c = idx >> 5, sl = idx & 31;
      *(uint4*)(qs + c * 256 + ((sl ^ (c & 31)) * 8)) =
          *(const uint4*)(qp + (size_t)c * kHW + nb + sl * 8);
      *(uint4*)(ks + c * 256 + ((sl ^ (c & 31)) * 8)) =
          *(const uint4*)(kp + (size_t)c * kHW + nb + sl * 8);
    }
    __syncthreads();
#pragma unroll
    for (int s = 0; s < 2; ++s) {
      const int slot = wv * 8 + s * 4 + fg;
      bfx8 aq[3], ak[3];
#pragma unroll
      for (int tt = 0; tt < 3; ++tt) {
        int c = tt * 16 + fr;
        aq[tt] = *(const bfx8*)(qs + c * 256 + ((slot ^ (c & 31)) * 8));
        ak[tt] = *(const bfx8*)(ks + c * 256 + ((slot ^ (c & 31)) * 8));
      }
#pragma unroll
      for (int i = 0; i < 3; ++i)
#pragma unroll
        for (int j = 0; j < 3; ++j)
          acc[i][j] = __builtin_amdgcn_mfma_f32_16x16x32_bf16(aq[i], ak[j], acc[i][j], 0, 0, 0);
    }
  }

  __syncthreads();                 // tile reads done; reuse LDS for reduce
  float* my = sred + wv * 2400;
#pragma unroll
  for (int i = 0; i < 3; ++i)
#pragma unroll
    for (int j = 0; j < 3; ++j)
#pragma unroll
      for (int r = 0; r < 4; ++r)
        my[(i * 16 + fg * 4 + r) * 50 + j * 16 + fr] = acc[i][j][r];
  __syncthreads();
  float* Sp = Spart + ((size_t)chunk * 32 + bh) * (kHD * kHD);
  for (int p = t; p < kHD * kHD; p += 256) {
    int idx = (p / kHD) * 50 + (p % kHD);
    Sp[p] = sred[idx] + sred[2400 + idx] + sred[4800 + idx] + sred[7200 + idx];
  }
}

// ---------------------------------------------------------------------------
// K3b: reduce partials, fold norms (eps=1e-12) + temperature, row softmax.
// ---------------------------------------------------------------------------
__global__ __launch_bounds__(256) void attn_softmax(
    const float* __restrict__ Spart, const float* __restrict__ ssqp,
    const float* __restrict__ temp, float* __restrict__ attn) {
  const int bh = blockIdx.x, b = bh >> 2, hh = bh & 3;
  const int t = threadIdx.x;
  __shared__ float S[kHD * kHD];
  __shared__ float qn[kHD], kinv[kHD];
  for (int p = t; p < kHD * kHD; p += 256) {
    float s = 0.f;
#pragma unroll
    for (int c = 0; c < kSCH; ++c) s += Spart[((size_t)c * 32 + bh) * (kHD * kHD) + p];
    S[p] = s;
  }
  if (t < 48) {
    qn[t] = sqrtf(ssqp[b * kC3 + hh * kHD + t]);
  } else if (t < 96) {
    kinv[t - 48] = 1.f / fmaxf(sqrtf(ssqp[b * kC3 + kC + hh * kHD + (t - 48)]), 1e-12f);
  }
  __syncthreads();
  if (t < 48) {
    const float T = temp[hh];
    const float sqr = T / fmaxf(qn[t], 1e-12f);
    float m = -3.4e38f;
    for (int d = 0; d < kHD; ++d) {
      float v = S[t * kHD + d] * sqr * kinv[d];
      S[t * kHD + d] = v;
      m = fmaxf(m, v);
    }
    float sum = 0.f;
    for (int d = 0; d < kHD; ++d) {
      float e = expf(S[t * kHD + d] - m);
      S[t * kHD + d] = e;
      sum += e;
    }
    const float inv = 1.f / sum;
    float* A = attn + (size_t)bh * (kHD * kHD) + t * kHD;
    for (int d = 0; d < kHD; ++d) A[d] = S[t * kHD + d] * inv;
  }
}

// ---------------------------------------------------------------------------
// K4: M[b][o][j=hh*48+d] = sum_c w_out[o][hh*48+c] * attn[b,hh,c,d]  (bf16)
// ---------------------------------------------------------------------------
__global__ __launch_bounds__(256) void make_m(
    const float* __restrict__ wout, const float* __restrict__ attn, u16* __restrict__ M) {
  int g = blockIdx.x * 256 + threadIdx.x;
  if (g >= kB * kC * kC) return;
  int j = g % kC;
  int o = (g / kC) % kC;
  int b = g / (kC * kC);
  int hh = j / kHD, d = j % kHD;
  const float* A = attn + (size_t)(b * 4 + hh) * (kHD * kHD) + d;
  const float* wo = wout + (size_t)o * kC + hh * kHD;
  float s = 0.f;
#pragma unroll
  for (int c = 0; c < kHD; ++c) s += wo[c] * A[c * kHD];
  M[g] = f2bfu(s);
}

// ---------------------------------------------------------------------------
extern "C" void kernel_launch(void* const* d_in, const int* in_sizes, int n_in,
                              void* d_out, int out_size, void* d_ws, size_t ws_size,
                              hipStream_t stream) {
  const float* x    = (const float*)d_in[0];
  const float* wqkv = (const float*)d_in[1];
  const float* wdw  = (const float*)d_in[2];
  const float* temp = (const float*)d_in[3];
  const float* wout = (const float*)d_in[4];

  size_t off = 0;
  u16* qkv1 = (u16*)((char*)d_ws + off); off += (size_t)kB * kC3 * kHW * 2;  // 151 MB
  u16* qkv2 = (u16*)((char*)d_ws + off); off += (size_t)kB * kC3 * kHW * 2;  // 151 MB
  u16* Wq   = (u16*)((char*)d_ws + off); off += (size_t)kC3 * kC * 2;
  float* ssqp = (float*)((char*)d_ws + off); off += (size_t)kB * kC3 * 4;
  if (off > ws_size) return;  // insufficient workspace -> fail visibly

  // attention scratch aliases qkv1 (dead after dwconv)
  float* Spart = (float*)qkv1;                              // 16*32*2304*4 = 4.7 MB
  float* attnb = Spart + (size_t)kSCH * 32 * kHD * kHD;
  u16*   Mb    = (u16*)(attnb + (size_t)32 * kHD * kHD);

  // P1: weight cast
  cast_f32_bf16<<<dim3((kC3 * kC + 255) / 256), 256, 0, stream>>>(wqkv, Wq, kC3 * kC);
  // K1: qkv1 = Wq @ x (MFMA, x [c][n] f32 direct); grid 3*128*8 = 3072 (%8==0)
  gemm_cn7<true, true><<<dim3(3 * 128 * kB), 512, 0, stream>>>(
      Wq, 0L, (const void*)x, (long)kC * kHW, (void*)qkv1, (long)kC3 * kHW, 3);
  // K2: depthwise 3x3 (+ q,k per-plane sumsq)
  dwconv3x3_v3<<<dim3(kB * kC3), 256, 0, stream>>>(qkv1, wdw, qkv2, ssqp);
  // K3: S partials (LDS-staged MFMA)
  qk_mfma_lds<<<dim3(kSCH, 32), 256, 0, stream>>>(qkv2, Spart);
  // K3b: reduce + normalize + softmax
  attn_softmax<<<dim3(32), 256, 0, stream>>>(Spart, ssqp, temp, attnb);
  // K4: M = w_out folded through attn (bf16)
  make_m<<<dim3((kB * kC * kC + 255) / 256), 256, 0, stream>>>(wout, attnb, Mb);
  // K5: out = M @ v (MFMA, v [c][n] bf16 direct, v read once); grid 1024 (%8==0)
  gemm_cn7<false, false><<<dim3(1 * 128 * kB), 512, 0, stream>>>(
      Mb, (long)kC * kC, (const void*)(qkv2 + (size_t)2 * kC * kHW),
      (long)kC3 * kHW, d_out, (long)kC * kHW, 1);
}

// Round 16
// 245.748 us; speedup vs baseline: 1.2726x; 1.2726x over previous
//
#include <hip/hip_runtime.h>
#include <hip/hip_bf16.h>

typedef unsigned short u16;
typedef unsigned int u32;

constexpr int kHW  = 16384;   // 128*128
constexpr int kC   = 192;
constexpr int kC3  = 576;
constexpr int kHD  = 48;
constexpr int kB   = 8;
constexpr int kSCH = 16;      // S-partial chunks (1024 n each)

typedef __attribute__((ext_vector_type(8))) short bfx8;  // 8 bf16 in 4 VGPRs
typedef __attribute__((ext_vector_type(4))) float fx4;

__device__ __forceinline__ float bfu2f(u32 u) { return __uint_as_float(u << 16); }
__device__ __forceinline__ u16 f2bfu(float f) {
  u32 x = __float_as_uint(f);
  return (u16)((x + 0x7fffu + ((x >> 16) & 1u)) >> 16);  // RNE
}
__device__ __forceinline__ u32 pack2(float a, float b) {
  union { __hip_bfloat162 h; u32 u; } cv;
  cv.h = __float22bfloat162_rn(make_float2(a, b));  // v_cvt_pk_bf16_f32
  return cv.u;
}

// ---------------------------------------------------------------------------
// P1: f32 -> bf16 cast (for w_qkv)
// ---------------------------------------------------------------------------
__global__ __launch_bounds__(256) void cast_f32_bf16(
    const float* __restrict__ in, u16* __restrict__ out, int n) {
  int i = blockIdx.x * 256 + threadIdx.x;
  if (i < n) out[i] = f2bfu(in[i]);
}

// ---------------------------------------------------------------------------
// K1/K5: MFMA GEMM, B consumed DIRECTLY from [k][n] row-major global layout.
// Out[b][o][n] = sum_k A[b?][o][k] * B[b][k][n], K = 192.
// Block tile 192o x 128n, 512 threads = 8 waves (wave-tile 48o x 64n, 4x2).
//
// ROUND-16: the prefetch pipeline, with BOTH prior bugs fixed:
//  (a) __launch_bounds__ 2nd arg is min BLOCKS/CU on this hipcc:
//      (512,4)->64-reg cap (r9-14 "spills" were this cap), (512,2)->128.
//  (b) r14/r15 passed prefetch arrays through lambda ARRAY PARAMETERS
//      (decay to pointer -> address taken -> SROA fails -> scratch arrays;
//      VGPR=68 + 293MB scratch WRITE at a 128-reg budget proved it).
//  Now: macros + NAMED variables only, no lambdas, no conditionals, fully
//  peeled 3 steps. Peak live: acc 48 + held A 12 + held B 16 + frags 28
//  + addr ~10 = ~114 < 128.
//
// B LDS layout (proven round 11): [n][k-pair],
//   word(n,p) = n*32 + (((p>>2) ^ s(n))*4 + (p&3)), s(n) = (n + (n>>3))&7
//   fragment = ONE ds_read_b128, identical k-map on A and B.
// Direct epilogue. Grid 1-D, o innermost + bijective XCD swizzle.
// ---------------------------------------------------------------------------
template <bool IN_F32, bool OUT_BF16>
__global__ __launch_bounds__(512, 2) void gemm_cn8(
    const u16* __restrict__ Abase, long aStride,
    const void* __restrict__ Bbase, long bStride,
    void* __restrict__ OutBase, long oStride, int nOB) {
  const int nwg = (int)gridDim.x;
  const int wg = ((int)blockIdx.x & 7) * (nwg >> 3) + ((int)blockIdx.x >> 3);
  const int o0 = (wg % nOB) * 192;
  const int rest = wg / nOB;
  const int n0 = (rest & 127) * 128;
  const int b  = rest >> 7;

  const int t = threadIdx.x;
  const int lane = t & 63, wv = t >> 6;     // 8 waves
  const int wo = wv & 3, wn = wv >> 2;      // wave-grid 4(o) x 2(n)
  const int fr = lane & 15, fg = lane >> 4;

  __shared__ u16 As[192 * 64];                // [o][k] swizzled, 24 KB
  __shared__ __align__(16) u32 Bs[128 * 32];  // [n][k-pair] swizzled, 16 KB

  const u16* A = Abase + (size_t)b * aStride;
  const float* BgF = (const float*)Bbase + (size_t)b * bStride;
  const u16*  BgH = (const u16*)Bbase + (size_t)b * bStride;

  fx4 acc[3][4];
#pragma unroll
  for (int m = 0; m < 3; ++m)
#pragma unroll
    for (int n = 0; n < 4; ++n) acc[m][n] = (fx4){0.f, 0.f, 0.f, 0.f};

  const int sp = t >> 4;            // staging pair index 0..31
  const int sn8 = (t & 15) * 8;     // staging n-oct base
  const int arow = t >> 3, asl = t & 7;
  const int phi = sp >> 2, plo = sp & 3;
  const int ar1 = arow + 64, ar2 = arow + 128;
  u16* const asDst0 = As + arow * 64 + ((asl ^ (arow & 7)) * 8);
  u16* const asDst1 = As + ar1 * 64 + ((asl ^ (ar1 & 7)) * 8);
  u16* const asDst2 = As + ar2 * 64 + ((asl ^ (ar2 & 7)) * 8);

// ---- macros: named variables only, constant indices ----
#define LOADA(K0, A0, A1, A2)                                                 \
  A0 = *(const uint4*)(A + (size_t)(o0 + arow) * kC + (K0) + asl * 8);        \
  A1 = *(const uint4*)(A + (size_t)(o0 + ar1) * kC + (K0) + asl * 8);         \
  A2 = *(const uint4*)(A + (size_t)(o0 + ar2) * kC + (K0) + asl * 8);
#define WRITEA(A0, A1, A2)                                                    \
  *(uint4*)asDst0 = A0; *(uint4*)asDst1 = A1; *(uint4*)asDst2 = A2;
#define LOADBF(K0, F0, F1, F2, F3)                                            \
  {                                                                           \
    const float* s0_ = BgF + (size_t)((K0) + 2 * sp) * kHW + n0 + sn8;        \
    F0 = *(const float4*)s0_;                                                 \
    F1 = *(const float4*)(s0_ + 4);                                           \
    F2 = *(const float4*)(s0_ + (size_t)kHW);                                 \
    F3 = *(const float4*)(s0_ + (size_t)kHW + 4);                             \
  }
#define LOADBH(K0, H0, H1)                                                    \
  {                                                                           \
    const u16* s0_ = BgH + (size_t)((K0) + 2 * sp) * kHW + n0 + sn8;          \
    H0 = *(const uint4*)s0_;                                                  \
    H1 = *(const uint4*)(s0_ + (size_t)kHW);                                  \
  }
#define WRITEB8(W0, W1, W2, W3, W4, W5, W6, W7)                               \
  {                                                                           \
    int n_, s_;                                                               \
    n_ = sn8 + 0; s_ = (n_ + (n_ >> 3)) & 7;                                  \
    Bs[n_ * 32 + (((phi ^ s_) << 2) | plo)] = W0;                             \
    n_ = sn8 + 1; s_ = (n_ + (n_ >> 3)) & 7;                                  \
    Bs[n_ * 32 + (((phi ^ s_) << 2) | plo)] = W1;                             \
    n_ = sn8 + 2; s_ = (n_ + (n_ >> 3)) & 7;                                  \
    Bs[n_ * 32 + (((phi ^ s_) << 2) | plo)] = W2;                             \
    n_ = sn8 + 3; s_ = (n_ + (n_ >> 3)) & 7;                                  \
    Bs[n_ * 32 + (((phi ^ s_) << 2) | plo)] = W3;                             \
    n_ = sn8 + 4; s_ = (n_ + (n_ >> 3)) & 7;                                  \
    Bs[n_ * 32 + (((phi ^ s_) << 2) | plo)] = W4;                             \
    n_ = sn8 + 5; s_ = (n_ + (n_ >> 3)) & 7;                                  \
    Bs[n_ * 32 + (((phi ^ s_) << 2) | plo)] = W5;                             \
    n_ = sn8 + 6; s_ = (n_ + (n_ >> 3)) & 7;                                  \
    Bs[n_ * 32 + (((phi ^ s_) << 2) | plo)] = W6;                             \
    n_ = sn8 + 7; s_ = (n_ + (n_ >> 3)) & 7;                                  \
    Bs[n_ * 32 + (((phi ^ s_) << 2) | plo)] = W7;                             \
  }
#define WRITEBF(F0, F1, F2, F3)                                               \
  WRITEB8(pack2(F0.x, F2.x), pack2(F0.y, F2.y), pack2(F0.z, F2.z),            \
          pack2(F0.w, F2.w), pack2(F1.x, F3.x), pack2(F1.y, F3.y),            \
          pack2(F1.z, F3.z), pack2(F1.w, F3.w))
#define WRITEBH(H0, H1)                                                       \
  {                                                                           \
    union { uint4 u; u16 e[8]; } a_, c_;                                      \
    a_.u = H0; c_.u = H1;                                                     \
    WRITEB8((u32)a_.e[0] | ((u32)c_.e[0] << 16),                              \
            (u32)a_.e[1] | ((u32)c_.e[1] << 16),                              \
            (u32)a_.e[2] | ((u32)c_.e[2] << 16),                              \
            (u32)a_.e[3] | ((u32)c_.e[3] << 16),                              \
            (u32)a_.e[4] | ((u32)c_.e[4] << 16),                              \
            (u32)a_.e[5] | ((u32)c_.e[5] << 16),                              \
            (u32)a_.e[6] | ((u32)c_.e[6] << 16),                              \
            (u32)a_.e[7] | ((u32)c_.e[7] << 16))                              \
  }
#define COMPUTE()                                                             \
  {                                                                           \
    _Pragma("unroll")                                                         \
    for (int ks = 0; ks < 2; ++ks) {                                          \
      bfx8 af[3], bfr[4];                                                     \
      _Pragma("unroll")                                                       \
      for (int m = 0; m < 3; ++m) {                                           \
        int row = wo * 48 + m * 16 + fr;                                      \
        af[m] = *(const bfx8*)(As + row * 64 + (((ks * 4 + fg) ^ (row & 7)) * 8)); \
      }                                                                       \
      _Pragma("unroll")                                                       \
      for (int nf = 0; nf < 4; ++nf) {                                        \
        int n = wn * 64 + nf * 16 + fr;                                       \
        int s = (n + (n >> 3)) & 7;                                           \
        union { uint4 u; bfx8 f; } cv;                                        \
        cv.u = *(const uint4*)(&Bs[n * 32 + (((ks * 4 + fg) ^ s) << 2)]);     \
        bfr[nf] = cv.f;                                                       \
      }                                                                       \
      _Pragma("unroll")                                                       \
      for (int m = 0; m < 3; ++m)                                             \
        _Pragma("unroll")                                                     \
        for (int n = 0; n < 4; ++n)                                           \
          acc[m][n] = __builtin_amdgcn_mfma_f32_16x16x32_bf16(af[m], bfr[n],  \
                                                              acc[m][n], 0, 0, 0); \
    }                                                                         \
  }

  // ---- hand-peeled 3-step pipeline, named register sets ----
  uint4 a00, a01, a02, a10, a11, a12, a20, a21, a22;
  float4 fA0, fA1, fA2, fA3, fB0, fB1, fB2, fB3, fC0, fC1, fC2, fC3;
  uint4 hA0, hA1, hB0, hB1, hC0, hC1;

  LOADA(0, a00, a01, a02);
  if constexpr (IN_F32) { LOADBF(0, fA0, fA1, fA2, fA3); } else { LOADBH(0, hA0, hA1); }
  WRITEA(a00, a01, a02);
  if constexpr (IN_F32) { WRITEBF(fA0, fA1, fA2, fA3); } else { WRITEBH(hA0, hA1); }
  LOADA(64, a10, a11, a12);                       // step-1 loads in flight
  if constexpr (IN_F32) { LOADBF(64, fB0, fB1, fB2, fB3); } else { LOADBH(64, hB0, hB1); }
  __syncthreads();
  COMPUTE();                                      // step 0 (hides step-1 latency)
  __syncthreads();
  WRITEA(a10, a11, a12);
  if constexpr (IN_F32) { WRITEBF(fB0, fB1, fB2, fB3); } else { WRITEBH(hB0, hB1); }
  LOADA(128, a20, a21, a22);                      // step-2 loads in flight
  if constexpr (IN_F32) { LOADBF(128, fC0, fC1, fC2, fC3); } else { LOADBH(128, hC0, hC1); }
  __syncthreads();
  COMPUTE();                                      // step 1 (hides step-2 latency)
  __syncthreads();
  WRITEA(a20, a21, a22);
  if constexpr (IN_F32) { WRITEBF(fC0, fC1, fC2, fC3); } else { WRITEBH(hC0, hC1); }
  __syncthreads();
  COMPUTE();                                      // step 2

#undef LOADA
#undef WRITEA
#undef LOADBF
#undef LOADBH
#undef WRITEB8
#undef WRITEBF
#undef WRITEBH
#undef COMPUTE

  // ---- direct epilogue (round-11 form) ----
  if constexpr (OUT_BF16) {
    u16* O = (u16*)OutBase + (size_t)b * oStride;
#pragma unroll
    for (int m = 0; m < 3; ++m)
#pragma unroll
      for (int n = 0; n < 4; ++n) {
        int col = n0 + wn * 64 + n * 16 + fr;
#pragma unroll
        for (int r = 0; r < 4; ++r)
          O[(size_t)(o0 + wo * 48 + m * 16 + fg * 4 + r) * kHW + col] = f2bfu(acc[m][n][r]);
      }
  } else {
    float* O = (float*)OutBase + (size_t)b * oStride;
#pragma unroll
    for (int m = 0; m < 3; ++m)
#pragma unroll
      for (int n = 0; n < 4; ++n) {
        int col = n0 + wn * 64 + n * 16 + fr;
#pragma unroll
        for (int r = 0; r < 4; ++r)
          O[(size_t)(o0 + wo * 48 + m * 16 + fg * 4 + r) * kHW + col] = acc[m][n][r];
      }
  }
}

// ---------------------------------------------------------------------------
// K2: depthwise 3x3 'SAME'. 8 output rows x 8 cols per thread, rolling row
// window; halo cols come from neighbor lanes via shfl (no scalar loads).
// Emits per-plane sum-of-squares for q,k channels.
// ---------------------------------------------------------------------------
__device__ __forceinline__ void load_row3(const u16* __restrict__ plane, int hh,
                                          int w8, float v[10]) {
  uint4 m = make_uint4(0u, 0u, 0u, 0u);
  if ((unsigned)hh <= 127u) m = *(const uint4*)(plane + hh * 128 + w8 * 8);
  u32 left  = __shfl_up(m.w >> 16, 1);        // prev lane's last col
  u32 right = __shfl_down(m.x & 0xffffu, 1);  // next lane's first col
  v[1] = bfu2f(m.x & 0xffffu); v[2] = bfu2f(m.x >> 16);
  v[3] = bfu2f(m.y & 0xffffu); v[4] = bfu2f(m.y >> 16);
  v[5] = bfu2f(m.z & 0xffffu); v[6] = bfu2f(m.z >> 16);
  v[7] = bfu2f(m.w & 0xffffu); v[8] = bfu2f(m.w >> 16);
  v[0] = (w8 > 0)  ? bfu2f(left)  : 0.f;
  v[9] = (w8 < 15) ? bfu2f(right) : 0.f;
}

__global__ __launch_bounds__(256) void dwconv3x3_v3(
    const u16* __restrict__ in, const float* __restrict__ wdw,
    u16* __restrict__ out, float* __restrict__ ssqp) {
  const int bc = blockIdx.x;            // plane index b*576+ch
  const int ch = bc % kC3;
  const int t = threadIdx.x;
  const int w8 = t & 15;
  const int h0 = (t >> 4) * 8;
  const u16* p = in + (size_t)bc * kHW;
  float wt[9];
#pragma unroll
  for (int j = 0; j < 9; ++j) wt[j] = wdw[ch * 9 + j];

  float v[3][10];
  load_row3(p, h0 - 1, w8, v[0]);
  load_row3(p, h0,     w8, v[1]);
  float ssq = 0.f;
  u16* op = out + (size_t)bc * kHW + h0 * 128 + w8 * 8;
#pragma unroll
  for (int r = 0; r < 8; ++r) {
    load_row3(p, h0 + r + 1, w8, v[(r + 2) % 3]);
    const float* r0 = v[r % 3];
    const float* r1 = v[(r + 1) % 3];
    const float* r2 = v[(r + 2) % 3];
    float o[8];
#pragma unroll
    for (int j = 0; j < 8; ++j) {
      o[j] = wt[0] * r0[j] + wt[1] * r0[j + 1] + wt[2] * r0[j + 2]
           + wt[3] * r1[j] + wt[4] * r1[j + 1] + wt[5] * r1[j + 2]
           + wt[6] * r2[j] + wt[7] * r2[j + 1] + wt[8] * r2[j + 2];
      ssq += o[j] * o[j];
    }
    *(uint4*)(op + r * 128) = make_uint4(pack2(o[0], o[1]), pack2(o[2], o[3]),
                                         pack2(o[4], o[5]), pack2(o[6], o[7]));
  }
  if (ch < 2 * kC) {  // q,k channels: block-uniform branch
#pragma unroll
    for (int d = 1; d < 64; d <<= 1) ssq += __shfl_xor(ssq, d);
    __shared__ float red[4];
    if ((t & 63) == 0) red[t >> 6] = ssq;
    __syncthreads();
    if (t == 0) ssqp[bc] = red[0] + red[1] + red[2] + red[3];
  }
}

// ---------------------------------------------------------------------------
// K3: LDS-staged MFMA split-K of S = q k^T. Block = (chunk of 1024 n, bh).
// ---------------------------------------------------------------------------
__global__ __launch_bounds__(256) void qk_mfma_lds(
    const u16* __restrict__ qkv2, float* __restrict__ Spart) {
  const int chunk = blockIdx.x;   // 0..15
  const int bh = blockIdx.y;      // 0..31
  const int b = bh >> 2, hh = bh & 3;
  const u16* qp = qkv2 + (size_t)(b * kC3 + hh * kHD) * kHW;
  const u16* kp = qp + (size_t)kC * kHW;

  __shared__ u16 smem[24576];     // 48 KB: qs | ks; sred aliases
  u16* qs = smem;
  u16* ks = smem + 12288;
  float* sred = (float*)smem;

  const int t = threadIdx.x;
  const int wv = t >> 6, lane = t & 63;
  const int fr = lane & 15, fg = lane >> 4;

  fx4 acc[3][3];
#pragma unroll
  for (int i = 0; i < 3; ++i)
#pragma unroll
    for (int j = 0; j < 3; ++j) acc[i][j] = (fx4){0.f, 0.f, 0.f, 0.f};

  for (int round = 0; round < 4; ++round) {
    if (round) __syncthreads();
    const int nb = chunk * 1024 + round * 256;
#pragma unroll
    for (int j = 0; j < 6; ++j) {   // 1536 uint4 per operand
      int idx = t + j * 256;
      int c = idx >> 5, sl = idx & 31;
      *(uint4*)(qs + c * 256 + ((sl ^ (c & 31)) * 8)) =
          *(const uint4*)(qp + (size_t)c * kHW + nb + sl * 8);
      *(uint4*)(ks + c * 256 + ((sl ^ (c & 31)) * 8)) =
          *(const uint4*)(kp + (size_t)c * kHW + nb + sl * 8);
    }
    __syncthreads();
#pragma unroll
    for (int s = 0; s < 2; ++s) {
      const int slot = wv * 8 + s * 4 + fg;
      bfx8 aq[3], ak[3];
#pragma unroll
      for (int tt = 0; tt < 3; ++tt) {
        int c = tt * 16 + fr;
        aq[tt] = *(const bfx8*)(qs + c * 256 + ((slot ^ (c & 31)) * 8));
        ak[tt] = *(const bfx8*)(ks + c * 256 + ((slot ^ (c & 31)) * 8));
      }
#pragma unroll
      for (int i = 0; i < 3; ++i)
#pragma unroll
        for (int j = 0; j < 3; ++j)
          acc[i][j] = __builtin_amdgcn_mfma_f32_16x16x32_bf16(aq[i], ak[j], acc[i][j], 0, 0, 0);
    }
  }

  __syncthreads();                 // tile reads done; reuse LDS for reduce
  float* my = sred + wv * 2400;
#pragma unroll
  for (int i = 0; i < 3; ++i)
#pragma unroll
    for (int j = 0; j < 3; ++j)
#pragma unroll
      for (int r = 0; r < 4; ++r)
        my[(i * 16 + fg * 4 + r) * 50 + j * 16 + fr] = acc[i][j][r];
  __syncthreads();
  float* Sp = Spart + ((size_t)chunk * 32 + bh) * (kHD * kHD);
  for (int p = t; p < kHD * kHD; p += 256) {
    int idx = (p / kHD) * 50 + (p % kHD);
    Sp[p] = sred[idx] + sred[2400 + idx] + sred[4800 + idx] + sred[7200 + idx];
  }
}

// ---------------------------------------------------------------------------
// K3b: reduce partials, fold norms (eps=1e-12) + temperature, row softmax.
// ---------------------------------------------------------------------------
__global__ __launch_bounds__(256) void attn_softmax(
    const float* __restrict__ Spart, const float* __restrict__ ssqp,
    const float* __restrict__ temp, float* __restrict__ attn) {
  const int bh = blockIdx.x, b = bh >> 2, hh = bh & 3;
  const int t = threadIdx.x;
  __shared__ float S[kHD * kHD];
  __shared__ float qn[kHD], kinv[kHD];
  for (int p = t; p < kHD * kHD; p += 256) {
    float s = 0.f;
#pragma unroll
    for (int c = 0; c < kSCH; ++c) s += Spart[((size_t)c * 32 + bh) * (kHD * kHD) + p];
    S[p] = s;
  }
  if (t < 48) {
    qn[t] = sqrtf(ssqp[b * kC3 + hh * kHD + t]);
  } else if (t < 96) {
    kinv[t - 48] = 1.f / fmaxf(sqrtf(ssqp[b * kC3 + kC + hh * kHD + (t - 48)]), 1e-12f);
  }
  __syncthreads();
  if (t < 48) {
    const float T = temp[hh];
    const float sqr = T / fmaxf(qn[t], 1e-12f);
    float m = -3.4e38f;
    for (int d = 0; d < kHD; ++d) {
      float v = S[t * kHD + d] * sqr * kinv[d];
      S[t * kHD + d] = v;
      m = fmaxf(m, v);
    }
    float sum = 0.f;
    for (int d = 0; d < kHD; ++d) {
      float e = expf(S[t * kHD + d] - m);
      S[t * kHD + d] = e;
      sum += e;
    }
    const float inv = 1.f / sum;
    float* A = attn + (size_t)bh * (kHD * kHD) + t * kHD;
    for (int d = 0; d < kHD; ++d) A[d] = S[t * kHD + d] * inv;
  }
}

// ---------------------------------------------------------------------------
// K4: M[b][o][j=hh*48+d] = sum_c w_out[o][hh*48+c] * attn[b,hh,c,d]  (bf16)
// ---------------------------------------------------------------------------
__global__ __launch_bounds__(256) void make_m(
    const float* __restrict__ wout, const float* __restrict__ attn, u16* __restrict__ M) {
  int g = blockIdx.x * 256 + threadIdx.x;
  if (g >= kB * kC * kC) return;
  int j = g % kC;
  int o = (g / kC) % kC;
  int b = g / (kC * kC);
  int hh = j / kHD, d = j % kHD;
  const float* A = attn + (size_t)(b * 4 + hh) * (kHD * kHD) + d;
  const float* wo = wout + (size_t)o * kC + hh * kHD;
  float s = 0.f;
#pragma unroll
  for (int c = 0; c < kHD; ++c) s += wo[c] * A[c * kHD];
  M[g] = f2bfu(s);
}

// ---------------------------------------------------------------------------
extern "C" void kernel_launch(void* const* d_in, const int* in_sizes, int n_in,
                              void* d_out, int out_size, void* d_ws, size_t ws_size,
                              hipStream_t stream) {
  const float* x    = (const float*)d_in[0];
  const float* wqkv = (const float*)d_in[1];
  const float* wdw  = (const float*)d_in[2];
  const float* temp = (const float*)d_in[3];
  const float* wout = (const float*)d_in[4];

  size_t off = 0;
  u16* qkv1 = (u16*)((char*)d_ws + off); off += (size_t)kB * kC3 * kHW * 2;  // 151 MB
  u16* qkv2 = (u16*)((char*)d_ws + off); off += (size_t)kB * kC3 * kHW * 2;  // 151 MB
  u16* Wq   = (u16*)((char*)d_ws + off); off += (size_t)kC3 * kC * 2;
  float* ssqp = (float*)((char*)d_ws + off); off += (size_t)kB * kC3 * 4;
  if (off > ws_size) return;  // insufficient workspace -> fail visibly

  // attention scratch aliases qkv1 (dead after dwconv)
  float* Spart = (float*)qkv1;                              // 16*32*2304*4 = 4.7 MB
  float* attnb = Spart + (size_t)kSCH * 32 * kHD * kHD;
  u16*   Mb    = (u16*)(attnb + (size_t)32 * kHD * kHD);

  // P1: weight cast
  cast_f32_bf16<<<dim3((kC3 * kC + 255) / 256), 256, 0, stream>>>(wqkv, Wq, kC3 * kC);
  // K1: qkv1 = Wq @ x (MFMA, x [c][n] f32 direct); grid 3*128*8 = 3072 (%8==0)
  gemm_cn8<true, true><<<dim3(3 * 128 * kB), 512, 0, stream>>>(
      Wq, 0L, (const void*)x, (long)kC * kHW, (void*)qkv1, (long)kC3 * kHW, 3);
  // K2: depthwise 3x3 (+ q,k per-plane sumsq)
  dwconv3x3_v3<<<dim3(kB * kC3), 256, 0, stream>>>(qkv1, wdw, qkv2, ssqp);
  // K3: S partials (LDS-staged MFMA)
  qk_mfma_lds<<<dim3(kSCH, 32), 256, 0, stream>>>(qkv2, Spart);
  // K3b: reduce + normalize + softmax
  attn_softmax<<<dim3(32), 256, 0, stream>>>(Spart, ssqp, temp, attnb);
  // K4: M = w_out folded through attn (bf16)
  make_m<<<dim3((kB * kC * kC + 255) / 256), 256, 0, stream>>>(wout, attnb, Mb);
  // K5: out = M @ v (MFMA, v [c][n] bf16 direct, v read once); grid 1024 (%8==0)
  gemm_cn8<false, false><<<dim3(1 * 128 * kB), 512, 0, stream>>>(
      Mb, (long)kC * kC, (const void*)(qkv2 + (size_t)2 * kC * kHW),
      (long)kC3 * kHW, d_out, (long)kC * kHW, 1);
}

// Round 17
// 243.370 us; speedup vs baseline: 1.2850x; 1.0098x over previous
//
#include <hip/hip_runtime.h>
#include <hip/hip_bf16.h>

typedef unsigned short u16;
typedef unsigned int u32;

constexpr int kHW  = 16384;   // 128*128
constexpr int kC   = 192;
constexpr int kC3  = 576;
constexpr int kHD  = 48;
constexpr int kB   = 8;
constexpr int kSCH = 16;      // S-partial chunks (1024 n each)

typedef __attribute__((ext_vector_type(8))) short bfx8;  // 8 bf16 in 4 VGPRs
typedef __attribute__((ext_vector_type(4))) float fx4;

__device__ __forceinline__ float bfu2f(u32 u) { return __uint_as_float(u << 16); }
__device__ __forceinline__ u16 f2bfu(float f) {
  u32 x = __float_as_uint(f);
  return (u16)((x + 0x7fffu + ((x >> 16) & 1u)) >> 16);  // RNE
}
__device__ __forceinline__ u32 pack2(float a, float b) {
  union { __hip_bfloat162 h; u32 u; } cv;
  cv.h = __float22bfloat162_rn(make_float2(a, b));  // v_cvt_pk_bf16_f32
  return cv.u;
}

// ---------------------------------------------------------------------------
// P1: f32 -> bf16 cast (for w_qkv)
// ---------------------------------------------------------------------------
__global__ __launch_bounds__(256) void cast_f32_bf16(
    const float* __restrict__ in, u16* __restrict__ out, int n) {
  int i = blockIdx.x * 256 + threadIdx.x;
  if (i < n) out[i] = f2bfu(in[i]);
}

// ---------------------------------------------------------------------------
// K1/K5: MFMA GEMM, B consumed DIRECTLY from [k][n] row-major global layout.
// Out[b][o][n] = sum_k A[b?][o][k] * B[b][k][n], K = 192.
// Block tile 192o x 128n, 512 threads = 8 waves (wave-tile 48o x 64n, 4x2).
//
// ROUND-17: keep round-16's clean hand-peeled prefetch pipeline (VGPR 72,
// zero spill -- both the launch-bounds cap (a) and lambda-array-SROA bug (b)
// fixed), but raise residency: (512,2) gave only 2 blocks/CU and occupancy
// collapsed 37%->21% (K1 106us). These kernels hide barrier stalls via
// cross-block TLP (m114), so ILP alone lost. (512,3): VGPR cap ~85 >= 72
// (pipeline still fits), 3 resident blocks/CU = 24 waves (LDS 40KB*3=120KB
// <= 160KB). First config with BOTH the pipeline and multi-block TLP.
//
// B LDS layout (proven round 11): [n][k-pair],
//   word(n,p) = n*32 + (((p>>2) ^ s(n))*4 + (p&3)), s(n) = (n + (n>>3))&7
//   fragment = ONE ds_read_b128, identical k-map on A and B.
// Direct epilogue. Grid 1-D, o innermost + bijective XCD swizzle.
// ---------------------------------------------------------------------------
template <bool IN_F32, bool OUT_BF16>
__global__ __launch_bounds__(512, 3) void gemm_cn9(
    const u16* __restrict__ Abase, long aStride,
    const void* __restrict__ Bbase, long bStride,
    void* __restrict__ OutBase, long oStride, int nOB) {
  const int nwg = (int)gridDim.x;
  const int wg = ((int)blockIdx.x & 7) * (nwg >> 3) + ((int)blockIdx.x >> 3);
  const int o0 = (wg % nOB) * 192;
  const int rest = wg / nOB;
  const int n0 = (rest & 127) * 128;
  const int b  = rest >> 7;

  const int t = threadIdx.x;
  const int lane = t & 63, wv = t >> 6;     // 8 waves
  const int wo = wv & 3, wn = wv >> 2;      // wave-grid 4(o) x 2(n)
  const int fr = lane & 15, fg = lane >> 4;

  __shared__ u16 As[192 * 64];                // [o][k] swizzled, 24 KB
  __shared__ __align__(16) u32 Bs[128 * 32];  // [n][k-pair] swizzled, 16 KB

  const u16* A = Abase + (size_t)b * aStride;
  const float* BgF = (const float*)Bbase + (size_t)b * bStride;
  const u16*  BgH = (const u16*)Bbase + (size_t)b * bStride;

  fx4 acc[3][4];
#pragma unroll
  for (int m = 0; m < 3; ++m)
#pragma unroll
    for (int n = 0; n < 4; ++n) acc[m][n] = (fx4){0.f, 0.f, 0.f, 0.f};

  const int sp = t >> 4;            // staging pair index 0..31
  const int sn8 = (t & 15) * 8;     // staging n-oct base
  const int arow = t >> 3, asl = t & 7;
  const int phi = sp >> 2, plo = sp & 3;
  const int ar1 = arow + 64, ar2 = arow + 128;
  u16* const asDst0 = As + arow * 64 + ((asl ^ (arow & 7)) * 8);
  u16* const asDst1 = As + ar1 * 64 + ((asl ^ (ar1 & 7)) * 8);
  u16* const asDst2 = As + ar2 * 64 + ((asl ^ (ar2 & 7)) * 8);

// ---- macros: named variables only, constant indices ----
#define LOADA(K0, A0, A1, A2)                                                 \
  A0 = *(const uint4*)(A + (size_t)(o0 + arow) * kC + (K0) + asl * 8);        \
  A1 = *(const uint4*)(A + (size_t)(o0 + ar1) * kC + (K0) + asl * 8);         \
  A2 = *(const uint4*)(A + (size_t)(o0 + ar2) * kC + (K0) + asl * 8);
#define WRITEA(A0, A1, A2)                                                    \
  *(uint4*)asDst0 = A0; *(uint4*)asDst1 = A1; *(uint4*)asDst2 = A2;
#define LOADBF(K0, F0, F1, F2, F3)                                            \
  {                                                                           \
    const float* s0_ = BgF + (size_t)((K0) + 2 * sp) * kHW + n0 + sn8;        \
    F0 = *(const float4*)s0_;                                                 \
    F1 = *(const float4*)(s0_ + 4);                                           \
    F2 = *(const float4*)(s0_ + (size_t)kHW);                                 \
    F3 = *(const float4*)(s0_ + (size_t)kHW + 4);                             \
  }
#define LOADBH(K0, H0, H1)                                                    \
  {                                                                           \
    const u16* s0_ = BgH + (size_t)((K0) + 2 * sp) * kHW + n0 + sn8;          \
    H0 = *(const uint4*)s0_;                                                  \
    H1 = *(const uint4*)(s0_ + (size_t)kHW);                                  \
  }
#define WRITEB8(W0, W1, W2, W3, W4, W5, W6, W7)                               \
  {                                                                           \
    int n_, s_;                                                               \
    n_ = sn8 + 0; s_ = (n_ + (n_ >> 3)) & 7;                                  \
    Bs[n_ * 32 + (((phi ^ s_) << 2) | plo)] = W0;                             \
    n_ = sn8 + 1; s_ = (n_ + (n_ >> 3)) & 7;                                  \
    Bs[n_ * 32 + (((phi ^ s_) << 2) | plo)] = W1;                             \
    n_ = sn8 + 2; s_ = (n_ + (n_ >> 3)) & 7;                                  \
    Bs[n_ * 32 + (((phi ^ s_) << 2) | plo)] = W2;                             \
    n_ = sn8 + 3; s_ = (n_ + (n_ >> 3)) & 7;                                  \
    Bs[n_ * 32 + (((phi ^ s_) << 2) | plo)] = W3;                             \
    n_ = sn8 + 4; s_ = (n_ + (n_ >> 3)) & 7;                                  \
    Bs[n_ * 32 + (((phi ^ s_) << 2) | plo)] = W4;                             \
    n_ = sn8 + 5; s_ = (n_ + (n_ >> 3)) & 7;                                  \
    Bs[n_ * 32 + (((phi ^ s_) << 2) | plo)] = W5;                             \
    n_ = sn8 + 6; s_ = (n_ + (n_ >> 3)) & 7;                                  \
    Bs[n_ * 32 + (((phi ^ s_) << 2) | plo)] = W6;                             \
    n_ = sn8 + 7; s_ = (n_ + (n_ >> 3)) & 7;                                  \
    Bs[n_ * 32 + (((phi ^ s_) << 2) | plo)] = W7;                             \
  }
#define WRITEBF(F0, F1, F2, F3)                                               \
  WRITEB8(pack2(F0.x, F2.x), pack2(F0.y, F2.y), pack2(F0.z, F2.z),            \
          pack2(F0.w, F2.w), pack2(F1.x, F3.x), pack2(F1.y, F3.y),            \
          pack2(F1.z, F3.z), pack2(F1.w, F3.w))
#define WRITEBH(H0, H1)                                                       \
  {                                                                           \
    union { uint4 u; u16 e[8]; } a_, c_;                                      \
    a_.u = H0; c_.u = H1;                                                     \
    WRITEB8((u32)a_.e[0] | ((u32)c_.e[0] << 16),                              \
            (u32)a_.e[1] | ((u32)c_.e[1] << 16),                              \
            (u32)a_.e[2] | ((u32)c_.e[2] << 16),                              \
            (u32)a_.e[3] | ((u32)c_.e[3] << 16),                              \
            (u32)a_.e[4] | ((u32)c_.e[4] << 16),                              \
            (u32)a_.e[5] | ((u32)c_.e[5] << 16),                              \
            (u32)a_.e[6] | ((u32)c_.e[6] << 16),                              \
            (u32)a_.e[7] | ((u32)c_.e[7] << 16))                              \
  }
#define COMPUTE()                                                             \
  {                                                                           \
    _Pragma("unroll")                                                         \
    for (int ks = 0; ks < 2; ++ks) {                                          \
      bfx8 af[3], bfr[4];                                                     \
      _Pragma("unroll")                                                       \
      for (int m = 0; m < 3; ++m) {                                           \
        int row = wo * 48 + m * 16 + fr;                                      \
        af[m] = *(const bfx8*)(As + row * 64 + (((ks * 4 + fg) ^ (row & 7)) * 8)); \
      }                                                                       \
      _Pragma("unroll")                                                       \
      for (int nf = 0; nf < 4; ++nf) {                                        \
        int n = wn * 64 + nf * 16 + fr;                                       \
        int s = (n + (n >> 3)) & 7;                                           \
        union { uint4 u; bfx8 f; } cv;                                        \
        cv.u = *(const uint4*)(&Bs[n * 32 + (((ks * 4 + fg) ^ s) << 2)]);     \
        bfr[nf] = cv.f;                                                       \
      }                                                                       \
      _Pragma("unroll")                                                       \
      for (int m = 0; m < 3; ++m)                                             \
        _Pragma("unroll")                                                     \
        for (int n = 0; n < 4; ++n)                                           \
          acc[m][n] = __builtin_amdgcn_mfma_f32_16x16x32_bf16(af[m], bfr[n],  \
                                                              acc[m][n], 0, 0, 0); \
    }                                                                         \
  }

  // ---- hand-peeled 3-step pipeline, named register sets ----
  uint4 a00, a01, a02, a10, a11, a12, a20, a21, a22;
  float4 fA0, fA1, fA2, fA3, fB0, fB1, fB2, fB3, fC0, fC1, fC2, fC3;
  uint4 hA0, hA1, hB0, hB1, hC0, hC1;

  LOADA(0, a00, a01, a02);
  if constexpr (IN_F32) { LOADBF(0, fA0, fA1, fA2, fA3); } else { LOADBH(0, hA0, hA1); }
  WRITEA(a00, a01, a02);
  if constexpr (IN_F32) { WRITEBF(fA0, fA1, fA2, fA3); } else { WRITEBH(hA0, hA1); }
  LOADA(64, a10, a11, a12);                       // step-1 loads in flight
  if constexpr (IN_F32) { LOADBF(64, fB0, fB1, fB2, fB3); } else { LOADBH(64, hB0, hB1); }
  __syncthreads();
  COMPUTE();                                      // step 0 (hides step-1 latency)
  __syncthreads();
  WRITEA(a10, a11, a12);
  if constexpr (IN_F32) { WRITEBF(fB0, fB1, fB2, fB3); } else { WRITEBH(hB0, hB1); }
  LOADA(128, a20, a21, a22);                      // step-2 loads in flight
  if constexpr (IN_F32) { LOADBF(128, fC0, fC1, fC2, fC3); } else { LOADBH(128, hC0, hC1); }
  __syncthreads();
  COMPUTE();                                      // step 1 (hides step-2 latency)
  __syncthreads();
  WRITEA(a20, a21, a22);
  if constexpr (IN_F32) { WRITEBF(fC0, fC1, fC2, fC3); } else { WRITEBH(hC0, hC1); }
  __syncthreads();
  COMPUTE();                                      // step 2

#undef LOADA
#undef WRITEA
#undef LOADBF
#undef LOADBH
#undef WRITEB8
#undef WRITEBF
#undef WRITEBH
#undef COMPUTE

  // ---- direct epilogue (round-11 form) ----
  if constexpr (OUT_BF16) {
    u16* O = (u16*)OutBase + (size_t)b * oStride;
#pragma unroll
    for (int m = 0; m < 3; ++m)
#pragma unroll
      for (int n = 0; n < 4; ++n) {
        int col = n0 + wn * 64 + n * 16 + fr;
#pragma unroll
        for (int r = 0; r < 4; ++r)
          O[(size_t)(o0 + wo * 48 + m * 16 + fg * 4 + r) * kHW + col] = f2bfu(acc[m][n][r]);
      }
  } else {
    float* O = (float*)OutBase + (size_t)b * oStride;
#pragma unroll
    for (int m = 0; m < 3; ++m)
#pragma unroll
      for (int n = 0; n < 4; ++n) {
        int col = n0 + wn * 64 + n * 16 + fr;
#pragma unroll
        for (int r = 0; r < 4; ++r)
          O[(size_t)(o0 + wo * 48 + m * 16 + fg * 4 + r) * kHW + col] = acc[m][n][r];
      }
  }
}

// ---------------------------------------------------------------------------
// K2: depthwise 3x3 'SAME'. 8 output rows x 8 cols per thread, rolling row
// window; halo cols come from neighbor lanes via shfl (no scalar loads).
// Emits per-plane sum-of-squares for q,k channels.
// ---------------------------------------------------------------------------
__device__ __forceinline__ void load_row3(const u16* __restrict__ plane, int hh,
                                          int w8, float v[10]) {
  uint4 m = make_uint4(0u, 0u, 0u, 0u);
  if ((unsigned)hh <= 127u) m = *(const uint4*)(plane + hh * 128 + w8 * 8);
  u32 left  = __shfl_up(m.w >> 16, 1);        // prev lane's last col
  u32 right = __shfl_down(m.x & 0xffffu, 1);  // next lane's first col
  v[1] = bfu2f(m.x & 0xffffu); v[2] = bfu2f(m.x >> 16);
  v[3] = bfu2f(m.y & 0xffffu); v[4] = bfu2f(m.y >> 16);
  v[5] = bfu2f(m.z & 0xffffu); v[6] = bfu2f(m.z >> 16);
  v[7] = bfu2f(m.w & 0xffffu); v[8] = bfu2f(m.w >> 16);
  v[0] = (w8 > 0)  ? bfu2f(left)  : 0.f;
  v[9] = (w8 < 15) ? bfu2f(right) : 0.f;
}

__global__ __launch_bounds__(256) void dwconv3x3_v3(
    const u16* __restrict__ in, const float* __restrict__ wdw,
    u16* __restrict__ out, float* __restrict__ ssqp) {
  const int bc = blockIdx.x;            // plane index b*576+ch
  const int ch = bc % kC3;
  const int t = threadIdx.x;
  const int w8 = t & 15;
  const int h0 = (t >> 4) * 8;
  const u16* p = in + (size_t)bc * kHW;
  float wt[9];
#pragma unroll
  for (int j = 0; j < 9; ++j) wt[j] = wdw[ch * 9 + j];

  float v[3][10];
  load_row3(p, h0 - 1, w8, v[0]);
  load_row3(p, h0,     w8, v[1]);
  float ssq = 0.f;
  u16* op = out + (size_t)bc * kHW + h0 * 128 + w8 * 8;
#pragma unroll
  for (int r = 0; r < 8; ++r) {
    load_row3(p, h0 + r + 1, w8, v[(r + 2) % 3]);
    const float* r0 = v[r % 3];
    const float* r1 = v[(r + 1) % 3];
    const float* r2 = v[(r + 2) % 3];
    float o[8];
#pragma unroll
    for (int j = 0; j < 8; ++j) {
      o[j] = wt[0] * r0[j] + wt[1] * r0[j + 1] + wt[2] * r0[j + 2]
           + wt[3] * r1[j] + wt[4] * r1[j + 1] + wt[5] * r1[j + 2]
           + wt[6] * r2[j] + wt[7] * r2[j + 1] + wt[8] * r2[j + 2];
      ssq += o[j] * o[j];
    }
    *(uint4*)(op + r * 128) = make_uint4(pack2(o[0], o[1]), pack2(o[2], o[3]),
                                         pack2(o[4], o[5]), pack2(o[6], o[7]));
  }
  if (ch < 2 * kC) {  // q,k channels: block-uniform branch
#pragma unroll
    for (int d = 1; d < 64; d <<= 1) ssq += __shfl_xor(ssq, d);
    __shared__ float red[4];
    if ((t & 63) == 0) red[t >> 6] = ssq;
    __syncthreads();
    if (t == 0) ssqp[bc] = red[0] + red[1] + red[2] + red[3];
  }
}

// ---------------------------------------------------------------------------
// K3: LDS-staged MFMA split-K of S = q k^T. Block = (chunk of 1024 n, bh).
// ---------------------------------------------------------------------------
__global__ __launch_bounds__(256) void qk_mfma_lds(
    const u16* __restrict__ qkv2, float* __restrict__ Spart) {
  const int chunk = blockIdx.x;   // 0..15
  const int bh = blockIdx.y;      // 0..31
  const int b = bh >> 2, hh = bh & 3;
  const u16* qp = qkv2 + (size_t)(b * kC3 + hh * kHD) * kHW;
  const u16* kp = qp + (size_t)kC * kHW;

  __shared__ u16 smem[24576];     // 48 KB: qs | ks; sred aliases
  u16* qs = smem;
  u16* ks = smem + 12288;
  float* sred = (float*)smem;

  const int t = threadIdx.x;
  const int wv = t >> 6, lane = t & 63;
  const int fr = lane & 15, fg = lane >> 4;

  fx4 acc[3][3];
#pragma unroll
  for (int i = 0; i < 3; ++i)
#pragma unroll
    for (int j = 0; j < 3; ++j) acc[i][j] = (fx4){0.f, 0.f, 0.f, 0.f};

  for (int round = 0; round < 4; ++round) {
    if (round) __syncthreads();
    const int nb = chunk * 1024 + round * 256;
#pragma unroll
    for (int j = 0; j < 6; ++j) {   // 1536 uint4 per operand
      int idx = t + j * 256;
      int c = idx >> 5, sl = idx & 31;
      *(uint4*)(qs + c * 256 + ((sl ^ (c & 31)) * 8)) =
          *(const uint4*)(qp + (size_t)c * kHW + nb + sl * 8);
      *(uint4*)(ks + c * 256 + ((sl ^ (c & 31)) * 8)) =
          *(const uint4*)(kp + (size_t)c * kHW + nb + sl * 8);
    }
    __syncthreads();
#pragma unroll
    for (int s = 0; s < 2; ++s) {
      const int slot = wv * 8 + s * 4 + fg;
      bfx8 aq[3], ak[3];
#pragma unroll
      for (int tt = 0; tt < 3; ++tt) {
        int c = tt * 16 + fr;
        aq[tt] = *(const bfx8*)(qs + c * 256 + ((slot ^ (c & 31)) * 8));
        ak[tt] = *(const bfx8*)(ks + c * 256 + ((slot ^ (c & 31)) * 8));
      }
#pragma unroll
      for (int i = 0; i < 3; ++i)
#pragma unroll
        for (int j = 0; j < 3; ++j)
          acc[i][j] = __builtin_amdgcn_mfma_f32_16x16x32_bf16(aq[i], ak[j], acc[i][j], 0, 0, 0);
    }
  }

  __syncthreads();                 // tile reads done; reuse LDS for reduce
  float* my = sred + wv * 2400;
#pragma unroll
  for (int i = 0; i < 3; ++i)
#pragma unroll
    for (int j = 0; j < 3; ++j)
#pragma unroll
      for (int r = 0; r < 4; ++r)
        my[(i * 16 + fg * 4 + r) * 50 + j * 16 + fr] = acc[i][j][r];
  __syncthreads();
  float* Sp = Spart + ((size_t)chunk * 32 + bh) * (kHD * kHD);
  for (int p = t; p < kHD * kHD; p += 256) {
    int idx = (p / kHD) * 50 + (p % kHD);
    Sp[p] = sred[idx] + sred[2400 + idx] + sred[4800 + idx] + sred[7200 + idx];
  }
}

// ---------------------------------------------------------------------------
// K3b: reduce partials, fold norms (eps=1e-12) + temperature, row softmax.
// ---------------------------------------------------------------------------
__global__ __launch_bounds__(256) void attn_softmax(
    const float* __restrict__ Spart, const float* __restrict__ ssqp,
    const float* __restrict__ temp, float* __restrict__ attn) {
  const int bh = blockIdx.x, b = bh >> 2, hh = bh & 3;
  const int t = threadIdx.x;
  __shared__ float S[kHD * kHD];
  __shared__ float qn[kHD], kinv[kHD];
  for (int p = t; p < kHD * kHD; p += 256) {
    float s = 0.f;
#pragma unroll
    for (int c = 0; c < kSCH; ++c) s += Spart[((size_t)c * 32 + bh) * (kHD * kHD) + p];
    S[p] = s;
  }
  if (t < 48) {
    qn[t] = sqrtf(ssqp[b * kC3 + hh * kHD + t]);
  } else if (t < 96) {
    kinv[t - 48] = 1.f / fmaxf(sqrtf(ssqp[b * kC3 + kC + hh * kHD + (t - 48)]), 1e-12f);
  }
  __syncthreads();
  if (t < 48) {
    const float T = temp[hh];
    const float sqr = T / fmaxf(qn[t], 1e-12f);
    float m = -3.4e38f;
    for (int d = 0; d < kHD; ++d) {
      float v = S[t * kHD + d] * sqr * kinv[d];
      S[t * kHD + d] = v;
      m = fmaxf(m, v);
    }
    float sum = 0.f;
    for (int d = 0; d < kHD; ++d) {
      float e = expf(S[t * kHD + d] - m);
      S[t * kHD + d] = e;
      sum += e;
    }
    const float inv = 1.f / sum;
    float* A = attn + (size_t)bh * (kHD * kHD) + t * kHD;
    for (int d = 0; d < kHD; ++d) A[d] = S[t * kHD + d] * inv;
  }
}

// ---------------------------------------------------------------------------
// K4: M[b][o][j=hh*48+d] = sum_c w_out[o][hh*48+c] * attn[b,hh,c,d]  (bf16)
// ---------------------------------------------------------------------------
__global__ __launch_bounds__(256) void make_m(
    const float* __restrict__ wout, const float* __restrict__ attn, u16* __restrict__ M) {
  int g = blockIdx.x * 256 + threadIdx.x;
  if (g >= kB * kC * kC) return;
  int j = g % kC;
  int o = (g / kC) % kC;
  int b = g / (kC * kC);
  int hh = j / kHD, d = j % kHD;
  const float* A = attn + (size_t)(b * 4 + hh) * (kHD * kHD) + d;
  const float* wo = wout + (size_t)o * kC + hh * kHD;
  float s = 0.f;
#pragma unroll
  for (int c = 0; c < kHD; ++c) s += wo[c] * A[c * kHD];
  M[g] = f2bfu(s);
}

// ---------------------------------------------------------------------------
extern "C" void kernel_launch(void* const* d_in, const int* in_sizes, int n_in,
                              void* d_out, int out_size, void* d_ws, size_t ws_size,
                              hipStream_t stream) {
  const float* x    = (const float*)d_in[0];
  const float* wqkv = (const float*)d_in[1];
  const float* wdw  = (const float*)d_in[2];
  const float* temp = (const float*)d_in[3];
  const float* wout = (const float*)d_in[4];

  size_t off = 0;
  u16* qkv1 = (u16*)((char*)d_ws + off); off += (size_t)kB * kC3 * kHW * 2;  // 151 MB
  u16* qkv2 = (u16*)((char*)d_ws + off); off += (size_t)kB * kC3 * kHW * 2;  // 151 MB
  u16* Wq   = (u16*)((char*)d_ws + off); off += (size_t)kC3 * kC * 2;
  float* ssqp = (float*)((char*)d_ws + off); off += (size_t)kB * kC3 * 4;
  if (off > ws_size) return;  // insufficient workspace -> fail visibly

  // attention scratch aliases qkv1 (dead after dwconv)
  float* Spart = (float*)qkv1;                              // 16*32*2304*4 = 4.7 MB
  float* attnb = Spart + (size_t)kSCH * 32 * kHD * kHD;
  u16*   Mb    = (u16*)(attnb + (size_t)32 * kHD * kHD);

  // P1: weight cast
  cast_f32_bf16<<<dim3((kC3 * kC + 255) / 256), 256, 0, stream>>>(wqkv, Wq, kC3 * kC);
  // K1: qkv1 = Wq @ x (MFMA, x [c][n] f32 direct); grid 3*128*8 = 3072 (%8==0)
  gemm_cn9<true, true><<<dim3(3 * 128 * kB), 512, 0, stream>>>(
      Wq, 0L, (const void*)x, (long)kC * kHW, (void*)qkv1, (long)kC3 * kHW, 3);
  // K2: depthwise 3x3 (+ q,k per-plane sumsq)
  dwconv3x3_v3<<<dim3(kB * kC3), 256, 0, stream>>>(qkv1, wdw, qkv2, ssqp);
  // K3: S partials (LDS-staged MFMA)
  qk_mfma_lds<<<dim3(kSCH, 32), 256, 0, stream>>>(qkv2, Spart);
  // K3b: reduce + normalize + softmax
  attn_softmax<<<dim3(32), 256, 0, stream>>>(Spart, ssqp, temp, attnb);
  // K4: M = w_out folded through attn (bf16)
  make_m<<<dim3((kB * kC * kC + 255) / 256), 256, 0, stream>>>(wout, attnb, Mb);
  // K5: out = M @ v (MFMA, v [c][n] bf16 direct, v read once); grid 1024 (%8==0)
  gemm_cn9<false, false><<<dim3(1 * 128 * kB), 512, 0, stream>>>(
      Mb, (long)kC * kC, (const void*)(qkv2 + (size_t)2 * kC * kHW),
      (long)kC3 * kHW, d_out, (long)kC * kHW, 1);
}